// Round 1
// baseline (623.516 us; speedup 1.0000x reference)
//
#include <hip/hip_runtime.h>
#include <hip/hip_bf16.h>

// LlamaAttention: B=2, T=2048, C=2048, H=16, D=128, rope theta 1e4, causal.
// Pipeline: cast->bf16, 3 proj GEMMs, RoPE, flash attn, out proj GEMM.

typedef __attribute__((ext_vector_type(4))) float f32x4;
typedef __attribute__((ext_vector_type(8))) short s16x8;
typedef __attribute__((ext_vector_type(4))) short s16x4;

typedef void __attribute__((address_space(1))) gvoid;
typedef void __attribute__((address_space(3))) svoid;
#define ASYNC16(ldsp, gp) __builtin_amdgcn_global_load_lds((gvoid*)(gp), (svoid*)(ldsp), 16, 0, 0)

__device__ __forceinline__ float bf2f(short b) {
  unsigned u = ((unsigned)(unsigned short)b) << 16;
  float f; __builtin_memcpy(&f, &u, 4); return f;
}
__device__ __forceinline__ short f2bf(float f) {
  unsigned u; __builtin_memcpy(&u, &f, 4);
  u += 0x7FFFu + ((u >> 16) & 1u);   // RTNE
  return (short)(u >> 16);
}

__device__ __forceinline__ f32x4 mfma16(s16x8 a, s16x8 b, f32x4 c) {
  return __builtin_amdgcn_mfma_f32_16x16x32_bf16(a, b, c, 0, 0, 0);
}

// ---------------- cast fp32 -> bf16 ----------------
__global__ __launch_bounds__(256)
void cvt_k(const float* __restrict__ in, short* __restrict__ out, int n4) {
  int i = blockIdx.x * 256 + threadIdx.x;
  if (i < n4) {
    f32x4 v = *(const f32x4*)&in[i * 4];
    s16x4 o;
#pragma unroll
    for (int e = 0; e < 4; e++) o[e] = f2bf(v[e]);
    *(s16x4*)&out[i * 4] = o;
  }
}

// ---------------- rope tables ----------------
__global__ void rope_tables_k(float* __restrict__ cosT, float* __restrict__ sinT) {
  int t = blockIdx.x, j = threadIdx.x;            // T x 64
  float inv = exp2f(-(float)j * 0.20762050593046f); // 10000^(-j/64)
  float a = (float)t * inv;
  cosT[t * 64 + j] = cosf(a);
  sinT[t * 64 + j] = sinf(a);
}

// ---------------- rope apply (in-place on q,k bf16) ----------------
__global__ __launch_bounds__(256)
void rope_apply_k(short* __restrict__ q, short* __restrict__ kk,
                  const float* __restrict__ cosT, const float* __restrict__ sinT) {
  int gid = blockIdx.x * 256 + threadIdx.x;  // rows(4096) * h(16) * jg(8)
  int jb = (gid & 7) * 8;
  int h  = (gid >> 3) & 15;
  int row = gid >> 7;            // b*T + t
  int t = row & 2047;
  long base = (long)row * 2048 + h * 128 + jb;
  float cc[8], ss[8];
  *(f32x4*)&cc[0] = *(const f32x4*)&cosT[t * 64 + jb];
  *(f32x4*)&cc[4] = *(const f32x4*)&cosT[t * 64 + jb + 4];
  *(f32x4*)&ss[0] = *(const f32x4*)&sinT[t * 64 + jb];
  *(f32x4*)&ss[4] = *(const f32x4*)&sinT[t * 64 + jb + 4];

  {
    s16x8 lo = *(s16x8*)&q[base];
    s16x8 hi = *(s16x8*)&q[base + 64];
    s16x8 nlo, nhi;
#pragma unroll
    for (int e = 0; e < 8; e++) {
      float a = bf2f(lo[e]), b = bf2f(hi[e]);
      nlo[e] = f2bf(a * cc[e] - b * ss[e]);
      nhi[e] = f2bf(b * cc[e] + a * ss[e]);
    }
    *(s16x8*)&q[base] = nlo;
    *(s16x8*)&q[base + 64] = nhi;
  }
  {
    s16x8 lo = *(s16x8*)&kk[base];
    s16x8 hi = *(s16x8*)&kk[base + 64];
    s16x8 nlo, nhi;
#pragma unroll
    for (int e = 0; e < 8; e++) {
      float a = bf2f(lo[e]), b = bf2f(hi[e]);
      nlo[e] = f2bf(a * cc[e] - b * ss[e]);
      nhi[e] = f2bf(b * cc[e] + a * ss[e]);
    }
    *(s16x8*)&kk[base] = nlo;
    *(s16x8*)&kk[base + 64] = nhi;
  }
}

// ---------------- GEMM: C[m][n] = sum_k A[m][k]*B[n][k] (both bf16, B^T input)
// m97 structure: 128x128 tile, BK=32, 4 waves, 4x4 16x16x32 frags/wave.
__device__ __forceinline__ void store_out(float* p, float v) { *p = v; }
__device__ __forceinline__ void store_out(short* p, float v) { *p = f2bf(v); }

template <typename OutT>
__global__ __launch_bounds__(256)
void gemm_bt_k(const short* __restrict__ A, const short* __restrict__ B,
               OutT* __restrict__ Cmat, int M, int N, int K) {
  __shared__ short As[128 * 32];
  __shared__ short Bs[128 * 32];
  const int tid = threadIdx.x;
  const int wave = tid >> 6, lane = tid & 63;
  const int lr = lane & 15, lk = lane >> 4;
  const int m0 = blockIdx.y * 128, n0 = blockIdx.x * 128;
  const int wr = (wave >> 1) * 64, wc = (wave & 1) * 64;

  f32x4 acc[4][4] = {};

  const int srow = tid >> 2;        // 0..63
  const int scol = (tid & 3) * 8;   // 0,8,16,24
  const short* aptr0 = A + (long)(m0 + srow) * K + scol;
  const short* aptr1 = A + (long)(m0 + 64 + srow) * K + scol;
  const short* bptr0 = B + (long)(n0 + srow) * K + scol;
  const short* bptr1 = B + (long)(n0 + 64 + srow) * K + scol;

  for (int kt = 0; kt < K; kt += 32) {
    __syncthreads();
    ASYNC16(&As[tid * 8],        aptr0 + kt);
    ASYNC16(&As[2048 + tid * 8], aptr1 + kt);
    ASYNC16(&Bs[tid * 8],        bptr0 + kt);
    ASYNC16(&Bs[2048 + tid * 8], bptr1 + kt);
    __syncthreads();
    s16x8 af[4], bfr[4];
#pragma unroll
    for (int i = 0; i < 4; i++)
      af[i] = *(const s16x8*)&As[(wr + i * 16 + lr) * 32 + lk * 8];
#pragma unroll
    for (int i = 0; i < 4; i++)
      bfr[i] = *(const s16x8*)&Bs[(wc + i * 16 + lr) * 32 + lk * 8];
#pragma unroll
    for (int mi = 0; mi < 4; mi++)
#pragma unroll
      for (int ni = 0; ni < 4; ni++)
        acc[mi][ni] = mfma16(af[mi], bfr[ni], acc[mi][ni]);
  }
#pragma unroll
  for (int mi = 0; mi < 4; mi++)
#pragma unroll
    for (int ni = 0; ni < 4; ni++)
#pragma unroll
      for (int r = 0; r < 4; r++) {
        int row = m0 + wr + mi * 16 + lk * 4 + r;   // C/D: row=(l>>4)*4+r
        int col = n0 + wc + ni * 16 + lr;           //      col=l&15
        store_out(&Cmat[(long)row * N + col], acc[mi][ni][r]);
      }
}

// ---------------- flash attention ----------------
// grid (T/64, H, B), 256 thr. QBLK=64 (16 rows/wave), KVBLK=32, D=128.
__global__ __launch_bounds__(256)
void attn_k(const short* __restrict__ q, const short* __restrict__ k,
            const short* __restrict__ v, short* __restrict__ o) {
  __shared__ short Ks[32 * 128];     // XOR-swizzled rows (256B rows)
  __shared__ short Vt[128 * 40];     // V^T, padded stride 40 elems
  __shared__ short Pl[4][16 * 32];   // per-wave P tile
  const int tid = threadIdx.x;
  const int wave = tid >> 6, lane = tid & 63;
  const int lr = lane & 15, lq = lane >> 4;
  const int qt = blockIdx.x, h = blockIdx.y, b = blockIdx.z;
  const int qbase = qt * 64;
  const long rowb = (long)b * 2048;

  s16x8 qf[4];
  {
    const short* qp = q + (rowb + qbase + wave * 16 + lr) * 2048 + h * 128 + lq * 8;
#pragma unroll
    for (int ks = 0; ks < 4; ks++) qf[ks] = *(const s16x8*)(qp + ks * 32);
  }
  f32x4 acc[8] = {};
  float mrun[4], lrun[4];
#pragma unroll
  for (int r = 0; r < 4; r++) { mrun[r] = -1e30f; lrun[r] = 0.f; }

  const int nkv = (qbase + 64) >> 5;   // 2*qt + 2 tiles
  const float scale = 0.08838834764831845f; // 1/sqrt(128)

  for (int ti = 0; ti < nkv; ti++) {
    const int kv0 = ti * 32;
    __syncthreads();
    // K tile: linear LDS dest, pre-swizzled global source (rule #21)
#pragma unroll
    for (int L = 0; L < 2; L++) {
      int ci = L * 256 + tid;
      int krow = ci >> 4, dslot = ci & 15;
      int col = (dslot ^ (krow & 7)) * 8;
      ASYNC16(&Ks[ci * 8], k + (rowb + kv0 + krow) * 2048 + h * 128 + col);
    }
    // V^T staging (reg transpose)
    {
      int kvr = tid & 31, dc = tid >> 5;
      const short* vp = v + (rowb + kv0 + kvr) * 2048 + h * 128 + dc * 16;
      s16x8 v0 = *(const s16x8*)vp;
      s16x8 v1 = *(const s16x8*)(vp + 8);
#pragma unroll
      for (int e = 0; e < 8; e++) Vt[(dc * 16 + e) * 40 + kvr] = v0[e];
#pragma unroll
      for (int e = 0; e < 8; e++) Vt[(dc * 16 + 8 + e) * 40 + kvr] = v1[e];
    }
    __syncthreads();

    // S = Q K^T  (A=Q rows, B=K rows as cols)
    f32x4 s[2] = {};
#pragma unroll
    for (int kvf = 0; kvf < 2; kvf++) {
      const int krow = kvf * 16 + lr;
#pragma unroll
      for (int ks = 0; ks < 4; ks++) {
        int doff = ks * 4 + lq;
        s16x8 kf = *(const s16x8*)&Ks[krow * 128 + ((doff ^ (krow & 7)) * 8)];
        s[kvf] = mfma16(qf[ks], kf, s[kvf]);
      }
    }
#pragma unroll
    for (int kvf = 0; kvf < 2; kvf++)
#pragma unroll
      for (int r = 0; r < 4; r++) s[kvf][r] *= scale;
    if (ti >= nkv - 2) {   // only diagonal tiles can need masking
#pragma unroll
      for (int kvf = 0; kvf < 2; kvf++) {
        int kvc = kv0 + kvf * 16 + lr;
#pragma unroll
        for (int r = 0; r < 4; r++) {
          int qr = qbase + wave * 16 + lq * 4 + r;
          if (kvc > qr) s[kvf][r] = -3.0e38f;
        }
      }
    }
    // online softmax; row r lives across the 16 lanes of this quarter-group
    float mt[4], sf[4], rs[4];
#pragma unroll
    for (int r = 0; r < 4; r++) mt[r] = fmaxf(s[0][r], s[1][r]);
#pragma unroll
    for (int d = 1; d < 16; d <<= 1)
#pragma unroll
      for (int r = 0; r < 4; r++) mt[r] = fmaxf(mt[r], __shfl_xor(mt[r], d));
#pragma unroll
    for (int r = 0; r < 4; r++) {
      float mn = fmaxf(mrun[r], mt[r]);
      sf[r] = __expf(mrun[r] - mn);
      mrun[r] = mn;
      rs[r] = 0.f;
    }
    short* pw = &Pl[wave][0];
#pragma unroll
    for (int kvf = 0; kvf < 2; kvf++)
#pragma unroll
      for (int r = 0; r < 4; r++) {
        float p = __expf(s[kvf][r] - mrun[r]);
        rs[r] += p;
        pw[(lq * 4 + r) * 32 + kvf * 16 + lr] = f2bf(p);
      }
#pragma unroll
    for (int d = 1; d < 16; d <<= 1)
#pragma unroll
      for (int r = 0; r < 4; r++) rs[r] += __shfl_xor(rs[r], d);
#pragma unroll
    for (int r = 0; r < 4; r++) lrun[r] = lrun[r] * sf[r] + rs[r];
#pragma unroll
    for (int df = 0; df < 8; df++)
#pragma unroll
      for (int r = 0; r < 4; r++) acc[df][r] *= sf[r];
    // PV: A = P (via LDS re-fragment, in-order LDS within wave), B = V^T rows
    s16x8 pf = *(const s16x8*)&pw[lr * 32 + lq * 8];
#pragma unroll
    for (int df = 0; df < 8; df++) {
      s16x8 vf = *(const s16x8*)&Vt[(df * 16 + lr) * 40 + lq * 8];
      acc[df] = mfma16(pf, vf, acc[df]);
    }
  }
#pragma unroll
  for (int r = 0; r < 4; r++) {
    float inv = 1.0f / lrun[r];
    long orow = rowb + qbase + wave * 16 + lq * 4 + r;
#pragma unroll
    for (int df = 0; df < 8; df++)
      o[orow * 2048 + h * 128 + df * 16 + lr] = f2bf(acc[df][r] * inv);
  }
}

extern "C" void kernel_launch(void* const* d_in, const int* in_sizes, int n_in,
                              void* d_out, int out_size, void* d_ws, size_t ws_size,
                              hipStream_t stream) {
  const float* x  = (const float*)d_in[0];
  const float* Wq = (const float*)d_in[1];
  const float* Wk = (const float*)d_in[2];
  const float* Wv = (const float*)d_in[3];
  const float* Wo = (const float*)d_in[4];
  float* out = (float*)d_out;

  char* p = (char*)d_ws;
  short* xb  = (short*)p; p += 8388608L * 2;
  short* wqb = (short*)p; p += 4194304L * 2;
  short* wkb = (short*)p; p += 4194304L * 2;
  short* wvb = (short*)p; p += 4194304L * 2;
  short* wob = (short*)p; p += 4194304L * 2;
  short* qb  = (short*)p; p += 8388608L * 2;
  short* kb  = (short*)p; p += 8388608L * 2;
  short* vb  = (short*)p; p += 8388608L * 2;
  short* ab  = (short*)p; p += 8388608L * 2;
  float* cosT = (float*)p; p += 131072L * 4;
  float* sinT = (float*)p; p += 131072L * 4;
  // total ws use: ~113 MB

  cvt_k<<<8192, 256, 0, stream>>>(x,  xb,  2097152);
  cvt_k<<<4096, 256, 0, stream>>>(Wq, wqb, 1048576);
  cvt_k<<<4096, 256, 0, stream>>>(Wk, wkb, 1048576);
  cvt_k<<<4096, 256, 0, stream>>>(Wv, wvb, 1048576);
  cvt_k<<<4096, 256, 0, stream>>>(Wo, wob, 1048576);
  rope_tables_k<<<2048, 64, 0, stream>>>(cosT, sinT);

  gemm_bt_k<short><<<dim3(16, 32), 256, 0, stream>>>(xb, wqb, qb, 4096, 2048, 2048);
  gemm_bt_k<short><<<dim3(16, 32), 256, 0, stream>>>(xb, wkb, kb, 4096, 2048, 2048);
  gemm_bt_k<short><<<dim3(16, 32), 256, 0, stream>>>(xb, wvb, vb, 4096, 2048, 2048);

  rope_apply_k<<<2048, 256, 0, stream>>>(qb, kb, cosT, sinT);

  attn_k<<<dim3(32, 16, 2), 256, 0, stream>>>(qb, kb, vb, ab);

  gemm_bt_k<float><<<dim3(16, 32), 256, 0, stream>>>(ab, wob, out, 4096, 2048, 2048);
}

// Round 4
// 444.447 us; speedup vs baseline: 1.4029x; 1.4029x over previous
//
#include <hip/hip_runtime.h>
#include <hip/hip_bf16.h>

// LlamaAttention: B=2, T=2048, C=2048, H=16, D=128, rope theta 1e4, causal.
// Pipeline: cast->bf16, fused QKV GEMM, RoPE, flash attn (paired causal
// blocks, KVBLK=64, K dbuf + V reg-prefetch), out proj GEMM.

typedef __attribute__((ext_vector_type(4))) float f32x4;
typedef __attribute__((ext_vector_type(8))) short s16x8;
typedef __attribute__((ext_vector_type(4))) short s16x4;

typedef void __attribute__((address_space(1))) gvoid;
typedef void __attribute__((address_space(3))) svoid;
#define ASYNC16(ldsp, gp) __builtin_amdgcn_global_load_lds((gvoid*)(gp), (svoid*)(ldsp), 16, 0, 0)

__device__ __forceinline__ float bf2f(short b) {
  unsigned u = ((unsigned)(unsigned short)b) << 16;
  float f; __builtin_memcpy(&f, &u, 4); return f;
}
__device__ __forceinline__ short f2bf(float f) {
  unsigned u; __builtin_memcpy(&u, &f, 4);
  u += 0x7FFFu + ((u >> 16) & 1u);   // RTNE
  return (short)(u >> 16);
}

__device__ __forceinline__ f32x4 mfma16(s16x8 a, s16x8 b, f32x4 c) {
  return __builtin_amdgcn_mfma_f32_16x16x32_bf16(a, b, c, 0, 0, 0);
}

// ---------------- cast fp32 -> bf16 ----------------
__global__ __launch_bounds__(256)
void cvt_k(const float* __restrict__ in, short* __restrict__ out, int n4) {
  int i = blockIdx.x * 256 + threadIdx.x;
  if (i < n4) {
    f32x4 v = *(const f32x4*)&in[i * 4];
    s16x4 o;
#pragma unroll
    for (int e = 0; e < 4; e++) o[e] = f2bf(v[e]);
    *(s16x4*)&out[i * 4] = o;
  }
}

// fused cast of the 4 weight matrices (each 2048x2048 = 1048576 x4-chunks)
__global__ __launch_bounds__(256)
void cvt_w4_k(const float* __restrict__ w0, const float* __restrict__ w1,
              const float* __restrict__ w2, const float* __restrict__ w3,
              short* __restrict__ o0, short* __restrict__ o1,
              short* __restrict__ o2, short* __restrict__ o3) {
  int i = blockIdx.x * 256 + threadIdx.x;   // [0, 4*1048576)
  int sel = i >> 20, j = i & 1048575;       // 1048576 chunks per weight
  const float* in = (sel == 0) ? w0 : (sel == 1) ? w1 : (sel == 2) ? w2 : w3;
  short* out = (sel == 0) ? o0 : (sel == 1) ? o1 : (sel == 2) ? o2 : o3;
  f32x4 v = *(const f32x4*)&in[j * 4];
  s16x4 o;
#pragma unroll
  for (int e = 0; e < 4; e++) o[e] = f2bf(v[e]);
  *(s16x4*)&out[j * 4] = o;
}

// ---------------- rope tables ----------------
__global__ void rope_tables_k(float* __restrict__ cosT, float* __restrict__ sinT) {
  int t = blockIdx.x, j = threadIdx.x;            // T x 64
  float inv = exp2f(-(float)j * 0.20762050593046f); // 10000^(-j/64)
  float a = (float)t * inv;
  cosT[t * 64 + j] = cosf(a);
  sinT[t * 64 + j] = sinf(a);
}

// ---------------- rope apply (in-place on q,k bf16) ----------------
__global__ __launch_bounds__(256)
void rope_apply_k(short* __restrict__ q, short* __restrict__ kk,
                  const float* __restrict__ cosT, const float* __restrict__ sinT) {
  int gid = blockIdx.x * 256 + threadIdx.x;  // rows(4096) * h(16) * jg(8)
  int jb = (gid & 7) * 8;
  int h  = (gid >> 3) & 15;
  int row = gid >> 7;            // b*T + t
  int t = row & 2047;
  long base = (long)row * 2048 + h * 128 + jb;
  float cc[8], ss[8];
  *(f32x4*)&cc[0] = *(const f32x4*)&cosT[t * 64 + jb];
  *(f32x4*)&cc[4] = *(const f32x4*)&cosT[t * 64 + jb + 4];
  *(f32x4*)&ss[0] = *(const f32x4*)&sinT[t * 64 + jb];
  *(f32x4*)&ss[4] = *(const f32x4*)&sinT[t * 64 + jb + 4];

  {
    s16x8 lo = *(s16x8*)&q[base];
    s16x8 hi = *(s16x8*)&q[base + 64];
    s16x8 nlo, nhi;
#pragma unroll
    for (int e = 0; e < 8; e++) {
      float a = bf2f(lo[e]), b = bf2f(hi[e]);
      nlo[e] = f2bf(a * cc[e] - b * ss[e]);
      nhi[e] = f2bf(b * cc[e] + a * ss[e]);
    }
    *(s16x8*)&q[base] = nlo;
    *(s16x8*)&q[base + 64] = nhi;
  }
  {
    s16x8 lo = *(s16x8*)&kk[base];
    s16x8 hi = *(s16x8*)&kk[base + 64];
    s16x8 nlo, nhi;
#pragma unroll
    for (int e = 0; e < 8; e++) {
      float a = bf2f(lo[e]), b = bf2f(hi[e]);
      nlo[e] = f2bf(a * cc[e] - b * ss[e]);
      nhi[e] = f2bf(b * cc[e] + a * ss[e]);
    }
    *(s16x8*)&kk[base] = nlo;
    *(s16x8*)&kk[base + 64] = nhi;
  }
}

// ---------------- GEMM core (m97: 128x128 tile, BK=32, 4 waves) ----------------
__device__ __forceinline__ void store_out(float* p, float v) { *p = v; }
__device__ __forceinline__ void store_out(short* p, float v) { *p = f2bf(v); }

template <typename OutT>
__device__ __forceinline__ void gemm_tile(const short* A, const short* B,
                                          OutT* Cmat, int m0, int n0,
                                          int K, int ldc,
                                          short* As, short* Bs) {
  const int tid = threadIdx.x;
  const int wave = tid >> 6, lane = tid & 63;
  const int lr = lane & 15, lk = lane >> 4;
  const int wr = (wave >> 1) * 64, wc = (wave & 1) * 64;

  f32x4 acc[4][4] = {};

  const int srow = tid >> 2;        // 0..63
  const int scol = (tid & 3) * 8;   // 0,8,16,24
  const short* aptr0 = A + (long)(m0 + srow) * K + scol;
  const short* aptr1 = A + (long)(m0 + 64 + srow) * K + scol;
  const short* bptr0 = B + (long)(srow) * K + scol;
  const short* bptr1 = B + (long)(64 + srow) * K + scol;

  for (int kt = 0; kt < K; kt += 32) {
    __syncthreads();
    ASYNC16(&As[tid * 8],        aptr0 + kt);
    ASYNC16(&As[2048 + tid * 8], aptr1 + kt);
    ASYNC16(&Bs[tid * 8],        bptr0 + kt);
    ASYNC16(&Bs[2048 + tid * 8], bptr1 + kt);
    __syncthreads();
    s16x8 af[4], bfr[4];
#pragma unroll
    for (int i = 0; i < 4; i++)
      af[i] = *(const s16x8*)&As[(wr + i * 16 + lr) * 32 + lk * 8];
#pragma unroll
    for (int i = 0; i < 4; i++)
      bfr[i] = *(const s16x8*)&Bs[(wc + i * 16 + lr) * 32 + lk * 8];
#pragma unroll
    for (int mi = 0; mi < 4; mi++)
#pragma unroll
      for (int ni = 0; ni < 4; ni++)
        acc[mi][ni] = mfma16(af[mi], bfr[ni], acc[mi][ni]);
  }
#pragma unroll
  for (int mi = 0; mi < 4; mi++)
#pragma unroll
    for (int ni = 0; ni < 4; ni++)
#pragma unroll
      for (int r = 0; r < 4; r++) {
        int row = m0 + wr + mi * 16 + lk * 4 + r;   // C/D: row=(l>>4)*4+r
        int col = n0 + wc + ni * 16 + lr;           //      col=l&15
        store_out(&Cmat[(long)row * ldc + col], acc[mi][ni][r]);
      }
}

// fused QKV: grid (48, 32); n-block selects which weight/output
__global__ __launch_bounds__(256)
void gemm_qkv_k(const short* __restrict__ A,
                const short* __restrict__ Bq, const short* __restrict__ Bk,
                const short* __restrict__ Bv,
                short* __restrict__ Cq, short* __restrict__ Ck,
                short* __restrict__ Cv, int K) {
  __shared__ short As[128 * 32];
  __shared__ short Bs[128 * 32];
  int nblk = blockIdx.x;                 // 0..47
  int sel = nblk >> 4;                   // 16 blocks per matrix
  int ncol = (nblk & 15) * 128;
  const short* B = (sel == 0) ? Bq : (sel == 1) ? Bk : Bv;
  short* C = (sel == 0) ? Cq : (sel == 1) ? Ck : Cv;
  gemm_tile<short>(A, B + (long)ncol * K, C, blockIdx.y * 128, ncol, K, 2048, As, Bs);
}

__global__ __launch_bounds__(256)
void gemm_out_k(const short* __restrict__ A, const short* __restrict__ B,
                float* __restrict__ C, int K) {
  __shared__ short As[128 * 32];
  __shared__ short Bs[128 * 32];
  gemm_tile<float>(A, B + (long)(blockIdx.x * 128) * K, C,
                   blockIdx.y * 128, blockIdx.x * 128, K, 2048, As, Bs);
}

// ---------------- flash attention ----------------
// grid (16, H, B), 256 thr. Block handles q-tiles {x, 31-x} (64 rows each):
// perfectly balanced causal work (33 kv64-tiles/block). KVBLK=64.
// K double-buffered via global_load_lds; V prefetched global->reg (issued
// before the K asyncs), transposed into padded LDS after PV barrier.
__global__ __launch_bounds__(256)
void attn_k(const short* __restrict__ q, const short* __restrict__ k,
            const short* __restrict__ v, short* __restrict__ o) {
  __shared__ short Ks[2][64 * 128];   // 32 KB, XOR-swizzled rows
  __shared__ short Vt[128 * 72];      // 18 KB, V^T padded stride 72
  __shared__ short Pl[4][16 * 72];    // 9 KB, per-wave P tile (stride 72)
  const int tid = threadIdx.x;
  const int wave = tid >> 6, lane = tid & 63;
  const int lr = lane & 15, lq = lane >> 4;
  const int h = blockIdx.y, b = blockIdx.z;
  const long rowb = (long)b * 2048;
  const int hoff = h * 128;
  const float scale = 0.08838834764831845f; // 1/sqrt(128)

  // V staging geometry: thread covers kv rows {vr, vr+1}, 16 cols
  const int vr = (tid & 31) * 2;
  const int vcol = (tid >> 5) * 16;

  for (int pass = 0; pass < 2; pass++) {
    const int qt = pass ? (31 - blockIdx.x) : blockIdx.x;
    const int qbase = qt * 64;
    const int nt = qt + 1;             // kv64 tiles

    s16x8 qf[4];
    {
      const short* qp = q + (rowb + qbase + wave * 16 + lr) * 2048 + hoff + lq * 8;
#pragma unroll
      for (int ks = 0; ks < 4; ks++) qf[ks] = *(const s16x8*)(qp + ks * 32);
    }
    f32x4 acc[8] = {};
    float mrun[4], lrun[4];
#pragma unroll
    for (int r = 0; r < 4; r++) { mrun[r] = -1e30f; lrun[r] = 0.f; }

    // ---- prologue: stage tile 0 ----
    s16x8 vl[4];
    {
      const short* vp = v + (rowb + vr) * 2048 + hoff + vcol;
      vl[0] = *(const s16x8*)vp;       vl[1] = *(const s16x8*)(vp + 8);
      vl[2] = *(const s16x8*)(vp + 2048); vl[3] = *(const s16x8*)(vp + 2048 + 8);
    }
#pragma unroll
    for (int L = 0; L < 4; L++) {
      int ci = L * 256 + tid;
      int krow = ci >> 4, dslot = ci & 15;
      int col = (dslot ^ (krow & 7)) * 8;
      ASYNC16(&Ks[0][ci * 8], k + (rowb + krow) * 2048 + hoff + col);
    }
#pragma unroll
    for (int e = 0; e < 16; e++) {
      int col = vcol + e;
      unsigned pk = (unsigned)(unsigned short)vl[e >> 3][e & 7]
                  | ((unsigned)(unsigned short)vl[2 + (e >> 3)][e & 7] << 16);
      *(unsigned*)&Vt[col * 72 + vr] = pk;
    }
    __syncthreads();

    int cur = 0;
    for (int ti = 0; ti < nt; ti++) {
      const int kv0 = ti * 64;
      const bool pre = (ti + 1 < nt);
      s16x8 vn[4];
      if (pre) {
        // V(next) -> regs FIRST (so its wait doesn't drain the K asyncs)
        const short* vp = v + (rowb + kv0 + 64 + vr) * 2048 + hoff + vcol;
        vn[0] = *(const s16x8*)vp;       vn[1] = *(const s16x8*)(vp + 8);
        vn[2] = *(const s16x8*)(vp + 2048); vn[3] = *(const s16x8*)(vp + 2048 + 8);
#pragma unroll
        for (int L = 0; L < 4; L++) {
          int ci = L * 256 + tid;
          int krow = ci >> 4, dslot = ci & 15;
          int col = (dslot ^ (krow & 7)) * 8;
          ASYNC16(&Ks[cur ^ 1][ci * 8], k + (rowb + kv0 + 64 + krow) * 2048 + hoff + col);
        }
      }
      // ---- S = Q K^T ----
      f32x4 s[4] = {};
#pragma unroll
      for (int kvf = 0; kvf < 4; kvf++) {
        const int krow = kvf * 16 + lr;
#pragma unroll
        for (int ks = 0; ks < 4; ks++) {
          int doff = ks * 4 + lq;
          s16x8 kf = *(const s16x8*)&Ks[cur][krow * 128 + ((doff ^ (krow & 7)) * 8)];
          s[kvf] = mfma16(qf[ks], kf, s[kvf]);
        }
      }
#pragma unroll
      for (int kvf = 0; kvf < 4; kvf++)
#pragma unroll
        for (int r = 0; r < 4; r++) s[kvf][r] *= scale;
      if (ti == nt - 1) {   // diagonal tile
#pragma unroll
        for (int kvf = 0; kvf < 4; kvf++) {
          int kvc = kv0 + kvf * 16 + lr;
#pragma unroll
          for (int r = 0; r < 4; r++) {
            int qr = qbase + wave * 16 + lq * 4 + r;
            if (kvc > qr) s[kvf][r] = -3.0e38f;
          }
        }
      }
      // ---- online softmax (rows across 16 lanes), defer-max THR=8 ----
      float mt[4], rs[4];
#pragma unroll
      for (int r = 0; r < 4; r++)
        mt[r] = fmaxf(fmaxf(s[0][r], s[1][r]), fmaxf(s[2][r], s[3][r]));
#pragma unroll
      for (int d = 1; d < 16; d <<= 1)
#pragma unroll
        for (int r = 0; r < 4; r++) mt[r] = fmaxf(mt[r], __shfl_xor(mt[r], d));
      int need = 0;
#pragma unroll
      for (int r = 0; r < 4; r++) need |= (mt[r] > mrun[r] + 8.f);
      if (__any(need)) {
#pragma unroll
        for (int r = 0; r < 4; r++) {
          float mn = fmaxf(mrun[r], mt[r]);
          float sf = __expf(mrun[r] - mn);
          mrun[r] = mn;
          lrun[r] *= sf;
#pragma unroll
          for (int df = 0; df < 8; df++) acc[df][r] *= sf;
        }
      }
      short* pw = &Pl[wave][0];
#pragma unroll
      for (int r = 0; r < 4; r++) rs[r] = 0.f;
#pragma unroll
      for (int kvf = 0; kvf < 4; kvf++)
#pragma unroll
        for (int r = 0; r < 4; r++) {
          float p = __expf(s[kvf][r] - mrun[r]);
          rs[r] += p;
          pw[(lq * 4 + r) * 72 + kvf * 16 + lr] = f2bf(p);
        }
#pragma unroll
      for (int d = 1; d < 16; d <<= 1)
#pragma unroll
        for (int r = 0; r < 4; r++) rs[r] += __shfl_xor(rs[r], d);
#pragma unroll
      for (int r = 0; r < 4; r++) lrun[r] += rs[r];
      // ---- PV ----
      s16x8 pf0 = *(const s16x8*)&pw[lr * 72 + lq * 8];
      s16x8 pf1 = *(const s16x8*)&pw[lr * 72 + 32 + lq * 8];
#pragma unroll
      for (int df = 0; df < 8; df++) {
        s16x8 vf0 = *(const s16x8*)&Vt[(df * 16 + lr) * 72 + lq * 8];
        s16x8 vf1 = *(const s16x8*)&Vt[(df * 16 + lr) * 72 + 32 + lq * 8];
        acc[df] = mfma16(pf0, vf0, acc[df]);
        acc[df] = mfma16(pf1, vf1, acc[df]);
      }
      __syncthreads();   // PV done everywhere; drains K asyncs (vmcnt 0)
      if (pre) {
#pragma unroll
        for (int e = 0; e < 16; e++) {
          int col = vcol + e;
          unsigned pk = (unsigned)(unsigned short)vn[e >> 3][e & 7]
                      | ((unsigned)(unsigned short)vn[2 + (e >> 3)][e & 7] << 16);
          *(unsigned*)&Vt[col * 72 + vr] = pk;
        }
        __syncthreads(); // Vt(next) visible; Ks[cur^1] ready
      }
      cur ^= 1;
    }
    // ---- epilogue ----
#pragma unroll
    for (int r = 0; r < 4; r++) {
      float inv = 1.0f / lrun[r];
      long orow = rowb + qbase + wave * 16 + lq * 4 + r;
#pragma unroll
      for (int df = 0; df < 8; df++)
        o[orow * 2048 + hoff + df * 16 + lr] = f2bf(acc[df][r] * inv);
    }
  }
}

extern "C" void kernel_launch(void* const* d_in, const int* in_sizes, int n_in,
                              void* d_out, int out_size, void* d_ws, size_t ws_size,
                              hipStream_t stream) {
  const float* x  = (const float*)d_in[0];
  const float* Wq = (const float*)d_in[1];
  const float* Wk = (const float*)d_in[2];
  const float* Wv = (const float*)d_in[3];
  const float* Wo = (const float*)d_in[4];
  float* out = (float*)d_out;

  char* p = (char*)d_ws;
  short* xb  = (short*)p; p += 8388608L * 2;
  short* wqb = (short*)p; p += 4194304L * 2;
  short* wkb = (short*)p; p += 4194304L * 2;
  short* wvb = (short*)p; p += 4194304L * 2;
  short* wob = (short*)p; p += 4194304L * 2;
  short* qb  = (short*)p; p += 8388608L * 2;
  short* kb  = (short*)p; p += 8388608L * 2;
  short* vb  = (short*)p; p += 8388608L * 2;
  short* ab  = (short*)p; p += 8388608L * 2;
  float* cosT = (float*)p; p += 131072L * 4;
  float* sinT = (float*)p; p += 131072L * 4;

  cvt_k<<<8192, 256, 0, stream>>>(x, xb, 2097152);
  cvt_w4_k<<<16384, 256, 0, stream>>>(Wq, Wk, Wv, Wo, wqb, wkb, wvb, wob);
  rope_tables_k<<<2048, 64, 0, stream>>>(cosT, sinT);

  gemm_qkv_k<<<dim3(48, 32), 256, 0, stream>>>(xb, wqb, wkb, wvb, qb, kb, vb, 2048);

  rope_apply_k<<<2048, 256, 0, stream>>>(qb, kb, cosT, sinT);

  attn_k<<<dim3(16, 16, 2), 256, 0, stream>>>(qb, kb, vb, ab);

  gemm_out_k<<<dim3(16, 32), 256, 0, stream>>>(ab, wob, out, 2048);
}

// Round 5
// 434.080 us; speedup vs baseline: 1.4364x; 1.0239x over previous
//
#include <hip/hip_runtime.h>
#include <hip/hip_bf16.h>

// LlamaAttention: B=2, T=2048, C=2048, H=16, D=128, rope theta 1e4, causal.
// Pipeline: cast->bf16, fused QKV GEMM (256^2 8-phase), RoPE, flash attn,
// out proj GEMM (256^2 8-phase).

typedef __attribute__((ext_vector_type(4))) float f32x4;
typedef __attribute__((ext_vector_type(8))) short s16x8;
typedef __attribute__((ext_vector_type(4))) short s16x4;

typedef void __attribute__((address_space(1))) gvoid;
typedef void __attribute__((address_space(3))) svoid;
#define ASYNC16(ldsp, gp) __builtin_amdgcn_global_load_lds((gvoid*)(gp), (svoid*)(ldsp), 16, 0, 0)

__device__ __forceinline__ float bf2f(short b) {
  unsigned u = ((unsigned)(unsigned short)b) << 16;
  float f; __builtin_memcpy(&f, &u, 4); return f;
}
__device__ __forceinline__ short f2bf(float f) {
  unsigned u; __builtin_memcpy(&u, &f, 4);
  u += 0x7FFFu + ((u >> 16) & 1u);   // RTNE
  return (short)(u >> 16);
}

__device__ __forceinline__ f32x4 mfma16(s16x8 a, s16x8 b, f32x4 c) {
  return __builtin_amdgcn_mfma_f32_16x16x32_bf16(a, b, c, 0, 0, 0);
}

// ---------------- cast fp32 -> bf16 ----------------
__global__ __launch_bounds__(256)
void cvt_k(const float* __restrict__ in, short* __restrict__ out, int n4) {
  int i = blockIdx.x * 256 + threadIdx.x;
  if (i < n4) {
    f32x4 v = *(const f32x4*)&in[i * 4];
    s16x4 o;
#pragma unroll
    for (int e = 0; e < 4; e++) o[e] = f2bf(v[e]);
    *(s16x4*)&out[i * 4] = o;
  }
}

// fused cast of the 4 weight matrices (each 2048x2048 = 1048576 x4-chunks)
__global__ __launch_bounds__(256)
void cvt_w4_k(const float* __restrict__ w0, const float* __restrict__ w1,
              const float* __restrict__ w2, const float* __restrict__ w3,
              short* __restrict__ o0, short* __restrict__ o1,
              short* __restrict__ o2, short* __restrict__ o3) {
  int i = blockIdx.x * 256 + threadIdx.x;   // [0, 4*1048576)
  int sel = i >> 20, j = i & 1048575;
  const float* in = (sel == 0) ? w0 : (sel == 1) ? w1 : (sel == 2) ? w2 : w3;
  short* out = (sel == 0) ? o0 : (sel == 1) ? o1 : (sel == 2) ? o2 : o3;
  f32x4 v = *(const f32x4*)&in[j * 4];
  s16x4 o;
#pragma unroll
  for (int e = 0; e < 4; e++) o[e] = f2bf(v[e]);
  *(s16x4*)&out[j * 4] = o;
}

// ---------------- rope tables ----------------
__global__ void rope_tables_k(float* __restrict__ cosT, float* __restrict__ sinT) {
  int t = blockIdx.x, j = threadIdx.x;            // T x 64
  float inv = exp2f(-(float)j * 0.20762050593046f); // 10000^(-j/64)
  float a = (float)t * inv;
  cosT[t * 64 + j] = cosf(a);
  sinT[t * 64 + j] = sinf(a);
}

// ---------------- rope apply (in-place on q,k bf16) ----------------
__global__ __launch_bounds__(256)
void rope_apply_k(short* __restrict__ q, short* __restrict__ kk,
                  const float* __restrict__ cosT, const float* __restrict__ sinT) {
  int gid = blockIdx.x * 256 + threadIdx.x;  // rows(4096) * h(16) * jg(8)
  int jb = (gid & 7) * 8;
  int h  = (gid >> 3) & 15;
  int row = gid >> 7;            // b*T + t
  int t = row & 2047;
  long base = (long)row * 2048 + h * 128 + jb;
  float cc[8], ss[8];
  *(f32x4*)&cc[0] = *(const f32x4*)&cosT[t * 64 + jb];
  *(f32x4*)&cc[4] = *(const f32x4*)&cosT[t * 64 + jb + 4];
  *(f32x4*)&ss[0] = *(const f32x4*)&sinT[t * 64 + jb];
  *(f32x4*)&ss[4] = *(const f32x4*)&sinT[t * 64 + jb + 4];

  {
    s16x8 lo = *(s16x8*)&q[base];
    s16x8 hi = *(s16x8*)&q[base + 64];
    s16x8 nlo, nhi;
#pragma unroll
    for (int e = 0; e < 8; e++) {
      float a = bf2f(lo[e]), b = bf2f(hi[e]);
      nlo[e] = f2bf(a * cc[e] - b * ss[e]);
      nhi[e] = f2bf(b * cc[e] + a * ss[e]);
    }
    *(s16x8*)&q[base] = nlo;
    *(s16x8*)&q[base + 64] = nhi;
  }
  {
    s16x8 lo = *(s16x8*)&kk[base];
    s16x8 hi = *(s16x8*)&kk[base + 64];
    s16x8 nlo, nhi;
#pragma unroll
    for (int e = 0; e < 8; e++) {
      float a = bf2f(lo[e]), b = bf2f(hi[e]);
      nlo[e] = f2bf(a * cc[e] - b * ss[e]);
      nhi[e] = f2bf(b * cc[e] + a * ss[e]);
    }
    *(s16x8*)&kk[base] = nlo;
    *(s16x8*)&kk[base + 64] = nhi;
  }
}

__device__ __forceinline__ void store_out(float* p, float v) { *p = v; }
__device__ __forceinline__ void store_out(short* p, float v) { *p = f2bf(v); }

// ---------------- 256^2 8-phase GEMM (T2+T3+T4+T5) ----------------
// C[m][n] = sum_k A[m][k]*B[n][k]; B pre-offset to its 256-row panel.
// 512 thr (8 waves 2Mx4N), BK=64, LDS 128KB dbuf, XOR-8 swizzled k-granules.
// Stage schedule per tile t: ph0:t+1.A1 ph1:t+1.B0 ph2:t+1.B1 (buf^1),
// ph3:t+2.A0 (current buf, region free after ph2). vmcnt(2) once per tile.

#define STAGE_A(Abase, buf, h, t)                                              \
  { ASYNC16(&As[(buf)*16384 + (h)*8192 + lin0*8],                              \
            (Abase) + (long)(m0 + (h)*128 + r0) * K + (t)*64 + kk0);           \
    ASYNC16(&As[(buf)*16384 + (h)*8192 + lin1*8],                              \
            (Abase) + (long)(m0 + (h)*128 + r1) * K + (t)*64 + kk1); }
#define STAGE_B(Bbase, buf, h, t)                                              \
  { ASYNC16(&Bs[(buf)*16384 + (h)*8192 + lin0*8],                              \
            (Bbase) + (long)((h)*128 + r0) * K + (t)*64 + kk0);                \
    ASYNC16(&Bs[(buf)*16384 + (h)*8192 + lin1*8],                              \
            (Bbase) + (long)((h)*128 + r1) * K + (t)*64 + kk1); }
#define LDA(mi, ks) (*(const s16x8*)&As[p*16384 +                              \
    (wr*128 + (mi)*16 + lr)*64 + (((ks)*4 + lk) ^ (lr & 7))*8])
#define LDB(ni, ks) (*(const s16x8*)&Bs[p*16384 +                              \
    (wc*64 + (ni)*16 + lr)*64 + (((ks)*4 + lk) ^ (lr & 7))*8])

template <typename OutT>
__device__ __forceinline__ void gemm8_tile(const short* __restrict__ A,
                                           const short* __restrict__ B,
                                           OutT* __restrict__ Cmat,
                                           int n0, int K, int ldc,
                                           short* As, short* Bs) {
  const int tid = threadIdx.x;
  const int wid = tid >> 6, lane = tid & 63;
  const int lr = lane & 15, lk = lane >> 4;
  const int wr = wid >> 2, wc = wid & 3;       // 2 x 4 waves
  const int m0 = blockIdx.y * 256;

  // staging geometry: thread covers 16B granules lin0, lin1 of each half-tile
  const int lin0 = wid * 128 + lane;
  const int lin1 = wid * 128 + 64 + lane;
  const int r0 = lin0 >> 3, r1 = lin1 >> 3;
  const int kk0 = ((lin0 & 7) ^ (r0 & 7)) * 8;   // inverse-swizzled source k
  const int kk1 = ((lin1 & 7) ^ (r1 & 7)) * 8;

  f32x4 acc[8][4] = {};
  const int NT = K >> 6;

  // ---- prologue: tile0 complete + tile1.A0 in flight ----
  STAGE_A(A, 0, 0, 0); STAGE_A(A, 0, 1, 0);
  STAGE_B(B, 0, 0, 0); STAGE_B(B, 0, 1, 0);
  STAGE_A(A, 1, 0, 1);
  asm volatile("s_waitcnt vmcnt(2)" ::: "memory");
  __builtin_amdgcn_sched_barrier(0);
  __builtin_amdgcn_s_barrier();

  for (int t = 0; t < NT; ++t) {
    const int p = t & 1;
    const bool s1 = (t + 1 < NT), s2 = (t + 2 < NT);
    s16x8 af[8], b0, b1;
    // ---- ph0: ks0 x n{0,1} ----
#pragma unroll
    for (int mi = 0; mi < 8; mi++) af[mi] = LDA(mi, 0);
    b0 = LDB(0, 0); b1 = LDB(1, 0);
    if (s1) STAGE_A(A, p ^ 1, 1, t + 1);
    __builtin_amdgcn_s_barrier();
    __builtin_amdgcn_s_setprio(1);
#pragma unroll
    for (int mi = 0; mi < 8; mi++) {
      acc[mi][0] = mfma16(af[mi], b0, acc[mi][0]);
      acc[mi][1] = mfma16(af[mi], b1, acc[mi][1]);
    }
    __builtin_amdgcn_s_setprio(0);
    __builtin_amdgcn_s_barrier();
    // ---- ph1: ks0 x n{2,3} ----
    b0 = LDB(2, 0); b1 = LDB(3, 0);
    if (s1) STAGE_B(B, p ^ 1, 0, t + 1);
    __builtin_amdgcn_s_barrier();
    __builtin_amdgcn_s_setprio(1);
#pragma unroll
    for (int mi = 0; mi < 8; mi++) {
      acc[mi][2] = mfma16(af[mi], b0, acc[mi][2]);
      acc[mi][3] = mfma16(af[mi], b1, acc[mi][3]);
    }
    __builtin_amdgcn_s_setprio(0);
    __builtin_amdgcn_s_barrier();
    // ---- ph2: ks1 x n{0,1} ----
#pragma unroll
    for (int mi = 0; mi < 8; mi++) af[mi] = LDA(mi, 1);
    b0 = LDB(0, 1); b1 = LDB(1, 1);
    if (s1) STAGE_B(B, p ^ 1, 1, t + 1);
    __builtin_amdgcn_s_barrier();
    __builtin_amdgcn_s_setprio(1);
#pragma unroll
    for (int mi = 0; mi < 8; mi++) {
      acc[mi][0] = mfma16(af[mi], b0, acc[mi][0]);
      acc[mi][1] = mfma16(af[mi], b1, acc[mi][1]);
    }
    __builtin_amdgcn_s_setprio(0);
    __builtin_amdgcn_s_barrier();
    // ---- ph3: ks1 x n{2,3} + tile-boundary counted vmcnt ----
    b0 = LDB(2, 1); b1 = LDB(3, 1);
    if (s2) {
      STAGE_A(A, p, 0, t + 2);
      asm volatile("s_waitcnt vmcnt(2)" ::: "memory");
    } else {
      asm volatile("s_waitcnt vmcnt(0)" ::: "memory");
    }
    __builtin_amdgcn_sched_barrier(0);
    __builtin_amdgcn_s_barrier();
    __builtin_amdgcn_s_setprio(1);
#pragma unroll
    for (int mi = 0; mi < 8; mi++) {
      acc[mi][2] = mfma16(af[mi], b0, acc[mi][2]);
      acc[mi][3] = mfma16(af[mi], b1, acc[mi][3]);
    }
    __builtin_amdgcn_s_setprio(0);
    __builtin_amdgcn_s_barrier();
  }
  // ---- epilogue ----
#pragma unroll
  for (int mi = 0; mi < 8; mi++)
#pragma unroll
    for (int ni = 0; ni < 4; ni++)
#pragma unroll
      for (int r = 0; r < 4; r++) {
        int row = m0 + wr * 128 + mi * 16 + lk * 4 + r;
        int col = n0 + wc * 64 + ni * 16 + lr;
        store_out(&Cmat[(long)row * ldc + col], acc[mi][ni][r]);
      }
}

// QKV: grid (24, 16); x-block selects weight/output
__global__ __launch_bounds__(512, 2)
void gemm8_qkv_k(const short* __restrict__ A,
                 const short* __restrict__ Bq, const short* __restrict__ Bk,
                 const short* __restrict__ Bv,
                 short* __restrict__ Cq, short* __restrict__ Ck,
                 short* __restrict__ Cv, int K) {
  __shared__ short As[2 * 16384];
  __shared__ short Bs[2 * 16384];
  int sel = blockIdx.x >> 3;
  int ncol = (blockIdx.x & 7) * 256;
  const short* B = (sel == 0) ? Bq : (sel == 1) ? Bk : Bv;
  short* C = (sel == 0) ? Cq : (sel == 1) ? Ck : Cv;
  gemm8_tile<short>(A, B + (long)ncol * K, C, ncol, K, 2048, As, Bs);
}

__global__ __launch_bounds__(512, 2)
void gemm8_out_k(const short* __restrict__ A, const short* __restrict__ B,
                 float* __restrict__ C, int K) {
  __shared__ short As[2 * 16384];
  __shared__ short Bs[2 * 16384];
  int ncol = blockIdx.x * 256;
  gemm8_tile<float>(A, B + (long)ncol * K, C, ncol, K, 2048, As, Bs);
}

// ---------------- flash attention (unchanged from round 4) ----------------
__global__ __launch_bounds__(256)
void attn_k(const short* __restrict__ q, const short* __restrict__ k,
            const short* __restrict__ v, short* __restrict__ o) {
  __shared__ short Ks[2][64 * 128];   // 32 KB, XOR-swizzled rows
  __shared__ short Vt[128 * 72];      // 18 KB, V^T padded stride 72
  __shared__ short Pl[4][16 * 72];    // 9 KB, per-wave P tile (stride 72)
  const int tid = threadIdx.x;
  const int wave = tid >> 6, lane = tid & 63;
  const int lr = lane & 15, lq = lane >> 4;
  const int h = blockIdx.y, b = blockIdx.z;
  const long rowb = (long)b * 2048;
  const int hoff = h * 128;
  const float scale = 0.08838834764831845f; // 1/sqrt(128)

  const int vr = (tid & 31) * 2;
  const int vcol = (tid >> 5) * 16;

  for (int pass = 0; pass < 2; pass++) {
    const int qt = pass ? (31 - blockIdx.x) : blockIdx.x;
    const int qbase = qt * 64;
    const int nt = qt + 1;             // kv64 tiles

    s16x8 qf[4];
    {
      const short* qp = q + (rowb + qbase + wave * 16 + lr) * 2048 + hoff + lq * 8;
#pragma unroll
      for (int ks = 0; ks < 4; ks++) qf[ks] = *(const s16x8*)(qp + ks * 32);
    }
    f32x4 acc[8] = {};
    float mrun[4], lrun[4];
#pragma unroll
    for (int r = 0; r < 4; r++) { mrun[r] = -1e30f; lrun[r] = 0.f; }

    // ---- prologue: stage tile 0 ----
    s16x8 vl[4];
    {
      const short* vp = v + (rowb + vr) * 2048 + hoff + vcol;
      vl[0] = *(const s16x8*)vp;       vl[1] = *(const s16x8*)(vp + 8);
      vl[2] = *(const s16x8*)(vp + 2048); vl[3] = *(const s16x8*)(vp + 2048 + 8);
    }
#pragma unroll
    for (int L = 0; L < 4; L++) {
      int ci = L * 256 + tid;
      int krow = ci >> 4, dslot = ci & 15;
      int col = (dslot ^ (krow & 7)) * 8;
      ASYNC16(&Ks[0][ci * 8], k + (rowb + krow) * 2048 + hoff + col);
    }
#pragma unroll
    for (int e = 0; e < 16; e++) {
      int col = vcol + e;
      unsigned pk = (unsigned)(unsigned short)vl[e >> 3][e & 7]
                  | ((unsigned)(unsigned short)vl[2 + (e >> 3)][e & 7] << 16);
      *(unsigned*)&Vt[col * 72 + vr] = pk;
    }
    __syncthreads();

    int cur = 0;
    for (int ti = 0; ti < nt; ti++) {
      const int kv0 = ti * 64;
      const bool pre = (ti + 1 < nt);
      s16x8 vn[4];
      if (pre) {
        const short* vp = v + (rowb + kv0 + 64 + vr) * 2048 + hoff + vcol;
        vn[0] = *(const s16x8*)vp;       vn[1] = *(const s16x8*)(vp + 8);
        vn[2] = *(const s16x8*)(vp + 2048); vn[3] = *(const s16x8*)(vp + 2048 + 8);
#pragma unroll
        for (int L = 0; L < 4; L++) {
          int ci = L * 256 + tid;
          int krow = ci >> 4, dslot = ci & 15;
          int col = (dslot ^ (krow & 7)) * 8;
          ASYNC16(&Ks[cur ^ 1][ci * 8], k + (rowb + kv0 + 64 + krow) * 2048 + hoff + col);
        }
      }
      // ---- S = Q K^T ----
      f32x4 s[4] = {};
#pragma unroll
      for (int kvf = 0; kvf < 4; kvf++) {
        const int krow = kvf * 16 + lr;
#pragma unroll
        for (int ks = 0; ks < 4; ks++) {
          int doff = ks * 4 + lq;
          s16x8 kf = *(const s16x8*)&Ks[cur][krow * 128 + ((doff ^ (krow & 7)) * 8)];
          s[kvf] = mfma16(qf[ks], kf, s[kvf]);
        }
      }
#pragma unroll
      for (int kvf = 0; kvf < 4; kvf++)
#pragma unroll
        for (int r = 0; r < 4; r++) s[kvf][r] *= scale;
      if (ti == nt - 1) {   // diagonal tile
#pragma unroll
        for (int kvf = 0; kvf < 4; kvf++) {
          int kvc = kv0 + kvf * 16 + lr;
#pragma unroll
          for (int r = 0; r < 4; r++) {
            int qr = qbase + wave * 16 + lq * 4 + r;
            if (kvc > qr) s[kvf][r] = -3.0e38f;
          }
        }
      }
      // ---- online softmax (defer-max THR=8) ----
      float mt[4], rs[4];
#pragma unroll
      for (int r = 0; r < 4; r++)
        mt[r] = fmaxf(fmaxf(s[0][r], s[1][r]), fmaxf(s[2][r], s[3][r]));
#pragma unroll
      for (int d = 1; d < 16; d <<= 1)
#pragma unroll
        for (int r = 0; r < 4; r++) mt[r] = fmaxf(mt[r], __shfl_xor(mt[r], d));
      int need = 0;
#pragma unroll
      for (int r = 0; r < 4; r++) need |= (mt[r] > mrun[r] + 8.f);
      if (__any(need)) {
#pragma unroll
        for (int r = 0; r < 4; r++) {
          float mn = fmaxf(mrun[r], mt[r]);
          float sf = __expf(mrun[r] - mn);
          mrun[r] = mn;
          lrun[r] *= sf;
#pragma unroll
          for (int df = 0; df < 8; df++) acc[df][r] *= sf;
        }
      }
      short* pw = &Pl[wave][0];
#pragma unroll
      for (int r = 0; r < 4; r++) rs[r] = 0.f;
#pragma unroll
      for (int kvf = 0; kvf < 4; kvf++)
#pragma unroll
        for (int r = 0; r < 4; r++) {
          float p = __expf(s[kvf][r] - mrun[r]);
          rs[r] += p;
          pw[(lq * 4 + r) * 72 + kvf * 16 + lr] = f2bf(p);
        }
#pragma unroll
      for (int d = 1; d < 16; d <<= 1)
#pragma unroll
        for (int r = 0; r < 4; r++) rs[r] += __shfl_xor(rs[r], d);
#pragma unroll
      for (int r = 0; r < 4; r++) lrun[r] += rs[r];
      // ---- PV ----
      s16x8 pf0 = *(const s16x8*)&pw[lr * 72 + lq * 8];
      s16x8 pf1 = *(const s16x8*)&pw[lr * 72 + 32 + lq * 8];
#pragma unroll
      for (int df = 0; df < 8; df++) {
        s16x8 vf0 = *(const s16x8*)&Vt[(df * 16 + lr) * 72 + lq * 8];
        s16x8 vf1 = *(const s16x8*)&Vt[(df * 16 + lr) * 72 + 32 + lq * 8];
        acc[df] = mfma16(pf0, vf0, acc[df]);
        acc[df] = mfma16(pf1, vf1, acc[df]);
      }
      __syncthreads();
      if (pre) {
#pragma unroll
        for (int e = 0; e < 16; e++) {
          int col = vcol + e;
          unsigned pk = (unsigned)(unsigned short)vn[e >> 3][e & 7]
                      | ((unsigned)(unsigned short)vn[2 + (e >> 3)][e & 7] << 16);
          *(unsigned*)&Vt[col * 72 + vr] = pk;
        }
        __syncthreads();
      }
      cur ^= 1;
    }
    // ---- epilogue ----
#pragma unroll
    for (int r = 0; r < 4; r++) {
      float inv = 1.0f / lrun[r];
      long orow = rowb + qbase + wave * 16 + lq * 4 + r;
#pragma unroll
      for (int df = 0; df < 8; df++)
        o[orow * 2048 + hoff + df * 16 + lr] = f2bf(acc[df][r] * inv);
    }
  }
}

extern "C" void kernel_launch(void* const* d_in, const int* in_sizes, int n_in,
                              void* d_out, int out_size, void* d_ws, size_t ws_size,
                              hipStream_t stream) {
  const float* x  = (const float*)d_in[0];
  const float* Wq = (const float*)d_in[1];
  const float* Wk = (const float*)d_in[2];
  const float* Wv = (const float*)d_in[3];
  const float* Wo = (const float*)d_in[4];
  float* out = (float*)d_out;

  char* p = (char*)d_ws;
  short* xb  = (short*)p; p += 8388608L * 2;
  short* wqb = (short*)p; p += 4194304L * 2;
  short* wkb = (short*)p; p += 4194304L * 2;
  short* wvb = (short*)p; p += 4194304L * 2;
  short* wob = (short*)p; p += 4194304L * 2;
  short* qb  = (short*)p; p += 8388608L * 2;
  short* kb  = (short*)p; p += 8388608L * 2;
  short* vb  = (short*)p; p += 8388608L * 2;
  short* ab  = (short*)p; p += 8388608L * 2;
  float* cosT = (float*)p; p += 131072L * 4;
  float* sinT = (float*)p; p += 131072L * 4;

  cvt_k<<<8192, 256, 0, stream>>>(x, xb, 2097152);
  cvt_w4_k<<<16384, 256, 0, stream>>>(Wq, Wk, Wv, Wo, wqb, wkb, wvb, wob);
  rope_tables_k<<<2048, 64, 0, stream>>>(cosT, sinT);

  gemm8_qkv_k<<<dim3(24, 16), 512, 0, stream>>>(xb, wqb, wkb, wvb, qb, kb, vb, 2048);

  rope_apply_k<<<2048, 256, 0, stream>>>(qb, kb, cosT, sinT);

  attn_k<<<dim3(16, 16, 2), 256, 0, stream>>>(qb, kb, vb, ab);

  gemm8_out_k<<<dim3(8, 16), 512, 0, stream>>>(ab, wob, out, 2048);
}

// Round 6
// 427.482 us; speedup vs baseline: 1.4586x; 1.0154x over previous
//
#include <hip/hip_runtime.h>
#include <hip/hip_bf16.h>

// LlamaAttention: B=2, T=2048, C=2048, H=16, D=128, rope theta 1e4, causal.
// Pipeline: cast->bf16, fused QKV GEMM (256^2, K-slice-chunked 4-phase
// pipeline, vmcnt(8)), RoPE, flash attn, out proj GEMM (256x128, 2-phase,
// vmcnt(6)).

typedef __attribute__((ext_vector_type(4))) float f32x4;
typedef __attribute__((ext_vector_type(8))) short s16x8;
typedef __attribute__((ext_vector_type(4))) short s16x4;

typedef void __attribute__((address_space(1))) gvoid;
typedef void __attribute__((address_space(3))) svoid;
#define ASYNC16(ldsp, gp) __builtin_amdgcn_global_load_lds((gvoid*)(gp), (svoid*)(ldsp), 16, 0, 0)
#define VMW(N) asm volatile("s_waitcnt vmcnt(" #N ")" ::: "memory")

__device__ __forceinline__ float bf2f(short b) {
  unsigned u = ((unsigned)(unsigned short)b) << 16;
  float f; __builtin_memcpy(&f, &u, 4); return f;
}
__device__ __forceinline__ short f2bf(float f) {
  unsigned u; __builtin_memcpy(&u, &f, 4);
  u += 0x7FFFu + ((u >> 16) & 1u);   // RTNE
  return (short)(u >> 16);
}

__device__ __forceinline__ f32x4 mfma16(s16x8 a, s16x8 b, f32x4 c) {
  return __builtin_amdgcn_mfma_f32_16x16x32_bf16(a, b, c, 0, 0, 0);
}

// ---------------- cast fp32 -> bf16 ----------------
__global__ __launch_bounds__(256)
void cvt_k(const float* __restrict__ in, short* __restrict__ out, int n4) {
  int i = blockIdx.x * 256 + threadIdx.x;
  if (i < n4) {
    f32x4 v = *(const f32x4*)&in[i * 4];
    s16x4 o;
#pragma unroll
    for (int e = 0; e < 4; e++) o[e] = f2bf(v[e]);
    *(s16x4*)&out[i * 4] = o;
  }
}

// fused cast of the 4 weight matrices (each 2048x2048 = 1048576 x4-chunks)
__global__ __launch_bounds__(256)
void cvt_w4_k(const float* __restrict__ w0, const float* __restrict__ w1,
              const float* __restrict__ w2, const float* __restrict__ w3,
              short* __restrict__ o0, short* __restrict__ o1,
              short* __restrict__ o2, short* __restrict__ o3) {
  int i = blockIdx.x * 256 + threadIdx.x;   // [0, 4*1048576)
  int sel = i >> 20, j = i & 1048575;
  const float* in = (sel == 0) ? w0 : (sel == 1) ? w1 : (sel == 2) ? w2 : w3;
  short* out = (sel == 0) ? o0 : (sel == 1) ? o1 : (sel == 2) ? o2 : o3;
  f32x4 v = *(const f32x4*)&in[j * 4];
  s16x4 o;
#pragma unroll
  for (int e = 0; e < 4; e++) o[e] = f2bf(v[e]);
  *(s16x4*)&out[j * 4] = o;
}

// ---------------- rope tables ----------------
__global__ void rope_tables_k(float* __restrict__ cosT, float* __restrict__ sinT) {
  int t = blockIdx.x, j = threadIdx.x;            // T x 64
  float inv = exp2f(-(float)j * 0.20762050593046f); // 10000^(-j/64)
  float a = (float)t * inv;
  cosT[t * 64 + j] = cosf(a);
  sinT[t * 64 + j] = sinf(a);
}

// ---------------- rope apply (in-place on q,k bf16) ----------------
__global__ __launch_bounds__(256)
void rope_apply_k(short* __restrict__ q, short* __restrict__ kk,
                  const float* __restrict__ cosT, const float* __restrict__ sinT) {
  int gid = blockIdx.x * 256 + threadIdx.x;  // rows(4096) * h(16) * jg(8)
  int jb = (gid & 7) * 8;
  int h  = (gid >> 3) & 15;
  int row = gid >> 7;            // b*T + t
  int t = row & 2047;
  long base = (long)row * 2048 + h * 128 + jb;
  float cc[8], ss[8];
  *(f32x4*)&cc[0] = *(const f32x4*)&cosT[t * 64 + jb];
  *(f32x4*)&cc[4] = *(const f32x4*)&cosT[t * 64 + jb + 4];
  *(f32x4*)&ss[0] = *(const f32x4*)&sinT[t * 64 + jb];
  *(f32x4*)&ss[4] = *(const f32x4*)&sinT[t * 64 + jb + 4];

  {
    s16x8 lo = *(s16x8*)&q[base];
    s16x8 hi = *(s16x8*)&q[base + 64];
    s16x8 nlo, nhi;
#pragma unroll
    for (int e = 0; e < 8; e++) {
      float a = bf2f(lo[e]), b = bf2f(hi[e]);
      nlo[e] = f2bf(a * cc[e] - b * ss[e]);
      nhi[e] = f2bf(b * cc[e] + a * ss[e]);
    }
    *(s16x8*)&q[base] = nlo;
    *(s16x8*)&q[base + 64] = nhi;
  }
  {
    s16x8 lo = *(s16x8*)&kk[base];
    s16x8 hi = *(s16x8*)&kk[base + 64];
    s16x8 nlo, nhi;
#pragma unroll
    for (int e = 0; e < 8; e++) {
      float a = bf2f(lo[e]), b = bf2f(hi[e]);
      nlo[e] = f2bf(a * cc[e] - b * ss[e]);
      nhi[e] = f2bf(b * cc[e] + a * ss[e]);
    }
    *(s16x8*)&kk[base] = nlo;
    *(s16x8*)&kk[base + 64] = nhi;
  }
}

// ---------------- QKV GEMM: 256x256, BK=64, K-slice chunks, 4 phases ----------------
// chunk(ks) = A[256 x k32] + B[256 x k32] (4 loads/thread). Stage schedule:
// t.ph0: c1(t+1)->buf^1; t.ph2: c0(t+2)->buf (region dead after t.ph1).
// vmcnt(8) at ph1/ph3 end forces chunks issued 5 phases earlier. Tail uses
// clamped dummy stages into dead regions to keep immediates uniform.
__global__ __launch_bounds__(512, 1)
void gemm_qkv8_k(const short* __restrict__ A,
                 const short* __restrict__ Bq, const short* __restrict__ Bk,
                 const short* __restrict__ Bv,
                 short* __restrict__ Cq, short* __restrict__ Ck,
                 short* __restrict__ Cv) {
  const int K = 2048, NT = 32;
  __shared__ short As[32768];   // [buf][ks][row 256][k 32] (granule-swizzled)
  __shared__ short Bs[32768];
  const int tid = threadIdx.x;
  const int wid = tid >> 6, lane = tid & 63;
  const int lr = lane & 15, lk = lane >> 4;
  const int wr = wid >> 2, wc = wid & 3;          // 2M x 4N waves
  const int sel = blockIdx.x >> 3;
  const int n0 = (blockIdx.x & 7) * 256;
  const int m0 = blockIdx.y * 256;
  const short* B = (sel == 0) ? Bq : (sel == 1) ? Bk : Bv;
  short* C = (sel == 0) ? Cq : (sel == 1) ? Ck : Cv;
  const short* PA = A + (long)m0 * K;
  const short* PB = B + (long)n0 * K;

  // staging: thread covers granules {tid, 512+tid} of each 16KB sub-chunk
  const int srow = tid >> 2;                                    // 0..127
  const int scol = (((tid & 3) ^ (srow & 3) ^ ((srow >> 2) & 3))) * 8;
  // read swizzle: phys granule = lk ^ pswz (row-dependent part is lr-only)
  const int gsw = ((lk ^ (lr & 3) ^ ((lr >> 2) & 3))) * 8;

  f32x4 acc[8][4] = {};

#define STG(buf, ks, tt)                                                       \
  { const long kof = (long)(tt) * 64 + (ks) * 32 + scol;                       \
    ASYNC16(&As[(buf)*16384 + (ks)*8192 + tid*8],        PA + (long)srow*K + kof);        \
    ASYNC16(&As[(buf)*16384 + (ks)*8192 + 4096 + tid*8], PA + (long)(srow+128)*K + kof);  \
    ASYNC16(&Bs[(buf)*16384 + (ks)*8192 + tid*8],        PB + (long)srow*K + kof);        \
    ASYNC16(&Bs[(buf)*16384 + (ks)*8192 + 4096 + tid*8], PB + (long)(srow+128)*K + kof); }
#define LDA1(buf, ks, mi) (*(const s16x8*)&As[(buf)*16384 + (ks)*8192 + (wr*128 + (mi)*16 + lr)*32 + gsw])
#define LDB1(buf, ks, ni) (*(const s16x8*)&Bs[(buf)*16384 + (ks)*8192 + (wc*64 + (ni)*16 + lr)*32 + gsw])

  // prologue: c0(0), c1(0), c0(1)
  STG(0, 0, 0); STG(0, 1, 0); STG(1, 0, 1);
  VMW(8);                       // forces c0(0)
  __builtin_amdgcn_sched_barrier(0);
  __builtin_amdgcn_s_barrier();

  for (int t = 0; t < NT; ++t) {
    const int p = t & 1;
    const int tc1 = (t + 1 < NT) ? t + 1 : NT - 1;
    const int tc0 = (t + 2 < NT) ? t + 2 : NT - 1;
    s16x8 af[8], b0, b1;
    // ---- ph0: ks0 x n{0,1} ----
#pragma unroll
    for (int mi = 0; mi < 8; mi++) af[mi] = LDA1(p, 0, mi);
    b0 = LDB1(p, 0, 0); b1 = LDB1(p, 0, 1);
    STG(p ^ 1, 1, tc1);                      // c1(t+1)
    __builtin_amdgcn_s_barrier();
    asm volatile("s_waitcnt lgkmcnt(0)" ::: "memory");
    __builtin_amdgcn_sched_barrier(0);
    __builtin_amdgcn_s_setprio(1);
#pragma unroll
    for (int mi = 0; mi < 8; mi++) {
      acc[mi][0] = mfma16(af[mi], b0, acc[mi][0]);
      acc[mi][1] = mfma16(af[mi], b1, acc[mi][1]);
    }
    __builtin_amdgcn_s_setprio(0);
    __builtin_amdgcn_s_barrier();
    // ---- ph1: ks0 x n{2,3} ----
    b0 = LDB1(p, 0, 2); b1 = LDB1(p, 0, 3);
    __builtin_amdgcn_s_barrier();
    asm volatile("s_waitcnt lgkmcnt(0)" ::: "memory");
    __builtin_amdgcn_sched_barrier(0);
    __builtin_amdgcn_s_setprio(1);
#pragma unroll
    for (int mi = 0; mi < 8; mi++) {
      acc[mi][2] = mfma16(af[mi], b0, acc[mi][2]);
      acc[mi][3] = mfma16(af[mi], b1, acc[mi][3]);
    }
    __builtin_amdgcn_s_setprio(0);
    VMW(8);                                  // forces c1(t)
    __builtin_amdgcn_sched_barrier(0);
    __builtin_amdgcn_s_barrier();
    // ---- ph2: ks1 x n{0,1} ----
#pragma unroll
    for (int mi = 0; mi < 8; mi++) af[mi] = LDA1(p, 1, mi);
    b0 = LDB1(p, 1, 0); b1 = LDB1(p, 1, 1);
    STG(p, 0, tc0);                          // c0(t+2) into freed region
    __builtin_amdgcn_s_barrier();
    asm volatile("s_waitcnt lgkmcnt(0)" ::: "memory");
    __builtin_amdgcn_sched_barrier(0);
    __builtin_amdgcn_s_setprio(1);
#pragma unroll
    for (int mi = 0; mi < 8; mi++) {
      acc[mi][0] = mfma16(af[mi], b0, acc[mi][0]);
      acc[mi][1] = mfma16(af[mi], b1, acc[mi][1]);
    }
    __builtin_amdgcn_s_setprio(0);
    __builtin_amdgcn_s_barrier();
    // ---- ph3: ks1 x n{2,3} ----
    b0 = LDB1(p, 1, 2); b1 = LDB1(p, 1, 3);
    __builtin_amdgcn_s_barrier();
    asm volatile("s_waitcnt lgkmcnt(0)" ::: "memory");
    __builtin_amdgcn_sched_barrier(0);
    __builtin_amdgcn_s_setprio(1);
#pragma unroll
    for (int mi = 0; mi < 8; mi++) {
      acc[mi][2] = mfma16(af[mi], b0, acc[mi][2]);
      acc[mi][3] = mfma16(af[mi], b1, acc[mi][3]);
    }
    __builtin_amdgcn_s_setprio(0);
    VMW(8);                                  // forces c0(t+1)
    __builtin_amdgcn_sched_barrier(0);
    __builtin_amdgcn_s_barrier();
  }
  VMW(0);                                    // drain tail dummies
  // ---- epilogue ----
#pragma unroll
  for (int mi = 0; mi < 8; mi++)
#pragma unroll
    for (int ni = 0; ni < 4; ni++)
#pragma unroll
      for (int r = 0; r < 4; r++) {
        int row = m0 + wr * 128 + mi * 16 + lk * 4 + r;
        int col = n0 + wc * 64 + ni * 16 + lr;
        C[(long)row * 2048 + col] = f2bf(acc[mi][ni][r]);
      }
#undef STG
#undef LDA1
#undef LDB1
}

// ---------------- out GEMM: 256x128, BK=64, 2 phases, vmcnt(6) ----------------
__global__ __launch_bounds__(512, 1)
void gemm_out8_k(const short* __restrict__ A, const short* __restrict__ Bw,
                 float* __restrict__ C) {
  const int K = 2048, NT = 32;
  __shared__ short As[32768];   // [buf][ks][row 256][k 32]
  __shared__ short Bs[16384];   // [buf][ks][row 128][k 32]
  const int tid = threadIdx.x;
  const int wid = tid >> 6, lane = tid & 63;
  const int lr = lane & 15, lk = lane >> 4;
  const int wr = wid >> 2, wc = wid & 3;          // 2M x 4N, wave = 128x32
  const int n0 = blockIdx.x * 128;
  const int m0 = blockIdx.y * 256;
  const short* PA = A + (long)m0 * K;
  const short* PB = Bw + (long)n0 * K;

  const int srow = tid >> 2;
  const int scol = (((tid & 3) ^ (srow & 3) ^ ((srow >> 2) & 3))) * 8;
  const int gsw = ((lk ^ (lr & 3) ^ ((lr >> 2) & 3))) * 8;

  f32x4 acc[8][2] = {};

#define STGO(buf, ks, tt)                                                      \
  { const long kof = (long)(tt) * 64 + (ks) * 32 + scol;                       \
    ASYNC16(&As[(buf)*16384 + (ks)*8192 + tid*8],        PA + (long)srow*K + kof);        \
    ASYNC16(&As[(buf)*16384 + (ks)*8192 + 4096 + tid*8], PA + (long)(srow+128)*K + kof);  \
    ASYNC16(&Bs[(buf)*8192 + (ks)*4096 + tid*8],         PB + (long)srow*K + kof); }
#define LDAO(buf, ks, mi) (*(const s16x8*)&As[(buf)*16384 + (ks)*8192 + (wr*128 + (mi)*16 + lr)*32 + gsw])
#define LDBO(buf, ks, ni) (*(const s16x8*)&Bs[(buf)*8192 + (ks)*4096 + (wc*32 + (ni)*16 + lr)*32 + gsw])

  STGO(0, 0, 0); STGO(0, 1, 0); STGO(1, 0, 1);
  VMW(6);                       // forces c0(0)
  __builtin_amdgcn_sched_barrier(0);
  __builtin_amdgcn_s_barrier();

  for (int t = 0; t < NT; ++t) {
    const int p = t & 1;
    const int tc1 = (t + 1 < NT) ? t + 1 : NT - 1;
    const int tc0 = (t + 2 < NT) ? t + 2 : NT - 1;
    s16x8 af[8], b0, b1;
    // ---- ph0: ks0 ----
#pragma unroll
    for (int mi = 0; mi < 8; mi++) af[mi] = LDAO(p, 0, mi);
    b0 = LDBO(p, 0, 0); b1 = LDBO(p, 0, 1);
    STGO(p ^ 1, 1, tc1);                     // c1(t+1)
    __builtin_amdgcn_s_barrier();
    asm volatile("s_waitcnt lgkmcnt(0)" ::: "memory");
    __builtin_amdgcn_sched_barrier(0);
    __builtin_amdgcn_s_setprio(1);
#pragma unroll
    for (int mi = 0; mi < 8; mi++) {
      acc[mi][0] = mfma16(af[mi], b0, acc[mi][0]);
      acc[mi][1] = mfma16(af[mi], b1, acc[mi][1]);
    }
    __builtin_amdgcn_s_setprio(0);
    VMW(6);                                  // forces c1(t)
    __builtin_amdgcn_sched_barrier(0);
    __builtin_amdgcn_s_barrier();
    // ---- ph1: ks1 ----
#pragma unroll
    for (int mi = 0; mi < 8; mi++) af[mi] = LDAO(p, 1, mi);
    b0 = LDBO(p, 1, 0); b1 = LDBO(p, 1, 1);
    STGO(p, 0, tc0);                         // c0(t+2)
    __builtin_amdgcn_s_barrier();
    asm volatile("s_waitcnt lgkmcnt(0)" ::: "memory");
    __builtin_amdgcn_sched_barrier(0);
    __builtin_amdgcn_s_setprio(1);
#pragma unroll
    for (int mi = 0; mi < 8; mi++) {
      acc[mi][0] = mfma16(af[mi], b0, acc[mi][0]);
      acc[mi][1] = mfma16(af[mi], b1, acc[mi][1]);
    }
    __builtin_amdgcn_s_setprio(0);
    VMW(6);                                  // forces c0(t+1)
    __builtin_amdgcn_sched_barrier(0);
    __builtin_amdgcn_s_barrier();
  }
  VMW(0);
#pragma unroll
  for (int mi = 0; mi < 8; mi++)
#pragma unroll
    for (int ni = 0; ni < 2; ni++)
#pragma unroll
      for (int r = 0; r < 4; r++) {
        int row = m0 + wr * 128 + mi * 16 + lk * 4 + r;
        int col = n0 + wc * 32 + ni * 16 + lr;
        C[(long)row * 2048 + col] = acc[mi][ni][r];
      }
#undef STGO
#undef LDAO
#undef LDBO
}

// ---------------- flash attention (unchanged) ----------------
__global__ __launch_bounds__(256)
void attn_k(const short* __restrict__ q, const short* __restrict__ k,
            const short* __restrict__ v, short* __restrict__ o) {
  __shared__ short Ks[2][64 * 128];   // 32 KB, XOR-swizzled rows
  __shared__ short Vt[128 * 72];      // 18 KB, V^T padded stride 72
  __shared__ short Pl[4][16 * 72];    // 9 KB, per-wave P tile (stride 72)
  const int tid = threadIdx.x;
  const int wave = tid >> 6, lane = tid & 63;
  const int lr = lane & 15, lq = lane >> 4;
  const int h = blockIdx.y, b = blockIdx.z;
  const long rowb = (long)b * 2048;
  const int hoff = h * 128;
  const float scale = 0.08838834764831845f; // 1/sqrt(128)

  const int vr = (tid & 31) * 2;
  const int vcol = (tid >> 5) * 16;

  for (int pass = 0; pass < 2; pass++) {
    const int qt = pass ? (31 - blockIdx.x) : blockIdx.x;
    const int qbase = qt * 64;
    const int nt = qt + 1;             // kv64 tiles

    s16x8 qf[4];
    {
      const short* qp = q + (rowb + qbase + wave * 16 + lr) * 2048 + hoff + lq * 8;
#pragma unroll
      for (int ks = 0; ks < 4; ks++) qf[ks] = *(const s16x8*)(qp + ks * 32);
    }
    f32x4 acc[8] = {};
    float mrun[4], lrun[4];
#pragma unroll
    for (int r = 0; r < 4; r++) { mrun[r] = -1e30f; lrun[r] = 0.f; }

    s16x8 vl[4];
    {
      const short* vp = v + (rowb + vr) * 2048 + hoff + vcol;
      vl[0] = *(const s16x8*)vp;       vl[1] = *(const s16x8*)(vp + 8);
      vl[2] = *(const s16x8*)(vp + 2048); vl[3] = *(const s16x8*)(vp + 2048 + 8);
    }
#pragma unroll
    for (int L = 0; L < 4; L++) {
      int ci = L * 256 + tid;
      int krow = ci >> 4, dslot = ci & 15;
      int col = (dslot ^ (krow & 7)) * 8;
      ASYNC16(&Ks[0][ci * 8], k + (rowb + krow) * 2048 + hoff + col);
    }
#pragma unroll
    for (int e = 0; e < 16; e++) {
      int col = vcol + e;
      unsigned pk = (unsigned)(unsigned short)vl[e >> 3][e & 7]
                  | ((unsigned)(unsigned short)vl[2 + (e >> 3)][e & 7] << 16);
      *(unsigned*)&Vt[col * 72 + vr] = pk;
    }
    __syncthreads();

    int cur = 0;
    for (int ti = 0; ti < nt; ti++) {
      const int kv0 = ti * 64;
      const bool pre = (ti + 1 < nt);
      s16x8 vn[4];
      if (pre) {
        const short* vp = v + (rowb + kv0 + 64 + vr) * 2048 + hoff + vcol;
        vn[0] = *(const s16x8*)vp;       vn[1] = *(const s16x8*)(vp + 8);
        vn[2] = *(const s16x8*)(vp + 2048); vn[3] = *(const s16x8*)(vp + 2048 + 8);
#pragma unroll
        for (int L = 0; L < 4; L++) {
          int ci = L * 256 + tid;
          int krow = ci >> 4, dslot = ci & 15;
          int col = (dslot ^ (krow & 7)) * 8;
          ASYNC16(&Ks[cur ^ 1][ci * 8], k + (rowb + kv0 + 64 + krow) * 2048 + hoff + col);
        }
      }
      f32x4 s[4] = {};
#pragma unroll
      for (int kvf = 0; kvf < 4; kvf++) {
        const int krow = kvf * 16 + lr;
#pragma unroll
        for (int ks = 0; ks < 4; ks++) {
          int doff = ks * 4 + lq;
          s16x8 kf = *(const s16x8*)&Ks[cur][krow * 128 + ((doff ^ (krow & 7)) * 8)];
          s[kvf] = mfma16(qf[ks], kf, s[kvf]);
        }
      }
#pragma unroll
      for (int kvf = 0; kvf < 4; kvf++)
#pragma unroll
        for (int r = 0; r < 4; r++) s[kvf][r] *= scale;
      if (ti == nt - 1) {
#pragma unroll
        for (int kvf = 0; kvf < 4; kvf++) {
          int kvc = kv0 + kvf * 16 + lr;
#pragma unroll
          for (int r = 0; r < 4; r++) {
            int qr = qbase + wave * 16 + lq * 4 + r;
            if (kvc > qr) s[kvf][r] = -3.0e38f;
          }
        }
      }
      float mt[4], rs[4];
#pragma unroll
      for (int r = 0; r < 4; r++)
        mt[r] = fmaxf(fmaxf(s[0][r], s[1][r]), fmaxf(s[2][r], s[3][r]));
#pragma unroll
      for (int d = 1; d < 16; d <<= 1)
#pragma unroll
        for (int r = 0; r < 4; r++) mt[r] = fmaxf(mt[r], __shfl_xor(mt[r], d));
      int need = 0;
#pragma unroll
      for (int r = 0; r < 4; r++) need |= (mt[r] > mrun[r] + 8.f);
      if (__any(need)) {
#pragma unroll
        for (int r = 0; r < 4; r++) {
          float mn = fmaxf(mrun[r], mt[r]);
          float sf = __expf(mrun[r] - mn);
          mrun[r] = mn;
          lrun[r] *= sf;
#pragma unroll
          for (int df = 0; df < 8; df++) acc[df][r] *= sf;
        }
      }
      short* pw = &Pl[wave][0];
#pragma unroll
      for (int r = 0; r < 4; r++) rs[r] = 0.f;
#pragma unroll
      for (int kvf = 0; kvf < 4; kvf++)
#pragma unroll
        for (int r = 0; r < 4; r++) {
          float p = __expf(s[kvf][r] - mrun[r]);
          rs[r] += p;
          pw[(lq * 4 + r) * 72 + kvf * 16 + lr] = f2bf(p);
        }
#pragma unroll
      for (int d = 1; d < 16; d <<= 1)
#pragma unroll
        for (int r = 0; r < 4; r++) rs[r] += __shfl_xor(rs[r], d);
#pragma unroll
      for (int r = 0; r < 4; r++) lrun[r] += rs[r];
      s16x8 pf0 = *(const s16x8*)&pw[lr * 72 + lq * 8];
      s16x8 pf1 = *(const s16x8*)&pw[lr * 72 + 32 + lq * 8];
#pragma unroll
      for (int df = 0; df < 8; df++) {
        s16x8 vf0 = *(const s16x8*)&Vt[(df * 16 + lr) * 72 + lq * 8];
        s16x8 vf1 = *(const s16x8*)&Vt[(df * 16 + lr) * 72 + 32 + lq * 8];
        acc[df] = mfma16(pf0, vf0, acc[df]);
        acc[df] = mfma16(pf1, vf1, acc[df]);
      }
      __syncthreads();
      if (pre) {
#pragma unroll
        for (int e = 0; e < 16; e++) {
          int col = vcol + e;
          unsigned pk = (unsigned)(unsigned short)vn[e >> 3][e & 7]
                      | ((unsigned)(unsigned short)vn[2 + (e >> 3)][e & 7] << 16);
          *(unsigned*)&Vt[col * 72 + vr] = pk;
        }
        __syncthreads();
      }
      cur ^= 1;
    }
#pragma unroll
    for (int r = 0; r < 4; r++) {
      float inv = 1.0f / lrun[r];
      long orow = rowb + qbase + wave * 16 + lq * 4 + r;
#pragma unroll
      for (int df = 0; df < 8; df++)
        o[orow * 2048 + hoff + df * 16 + lr] = f2bf(acc[df][r] * inv);
    }
  }
}

extern "C" void kernel_launch(void* const* d_in, const int* in_sizes, int n_in,
                              void* d_out, int out_size, void* d_ws, size_t ws_size,
                              hipStream_t stream) {
  const float* x  = (const float*)d_in[0];
  const float* Wq = (const float*)d_in[1];
  const float* Wk = (const float*)d_in[2];
  const float* Wv = (const float*)d_in[3];
  const float* Wo = (const float*)d_in[4];
  float* out = (float*)d_out;

  char* p = (char*)d_ws;
  short* xb  = (short*)p; p += 8388608L * 2;
  short* wqb = (short*)p; p += 4194304L * 2;
  short* wkb = (short*)p; p += 4194304L * 2;
  short* wvb = (short*)p; p += 4194304L * 2;
  short* wob = (short*)p; p += 4194304L * 2;
  short* qb  = (short*)p; p += 8388608L * 2;
  short* kb  = (short*)p; p += 8388608L * 2;
  short* vb  = (short*)p; p += 8388608L * 2;
  short* ab  = (short*)p; p += 8388608L * 2;
  float* cosT = (float*)p; p += 131072L * 4;
  float* sinT = (float*)p; p += 131072L * 4;

  cvt_k<<<8192, 256, 0, stream>>>(x, xb, 2097152);
  cvt_w4_k<<<16384, 256, 0, stream>>>(Wq, Wk, Wv, Wo, wqb, wkb, wvb, wob);
  rope_tables_k<<<2048, 64, 0, stream>>>(cosT, sinT);

  gemm_qkv8_k<<<dim3(24, 16), 512, 0, stream>>>(xb, wqb, wkb, wvb, qb, kb, vb);

  rope_apply_k<<<2048, 256, 0, stream>>>(qb, kb, cosT, sinT);

  attn_k<<<dim3(16, 16, 2), 256, 0, stream>>>(qb, kb, vb, ab);

  gemm_out8_k<<<dim3(16, 16), 512, 0, stream>>>(ab, wob, out);
}